// Round 1
// baseline (110.188 us; speedup 1.0000x reference)
//
#include <hip/hip_runtime.h>

#define B_ 16
#define H_ 64
#define W_ 64
#define C_ 512
#define NG 16

#define WT 16      // strip width (output cols per WG)
#define SEG 16     // rows per segment

#define SLOT_BYTES (18*512*2)          // one staged row (18 cols x 512 ch bf16) = 18432
#define XS_BYTES   (3*SLOT_BYTES)      // 3-row rolling window = 55296
#define OROW_OFF   XS_BYTES
#define OROW_BYTES (16*512*4)          // one output row fp32 = 32768
#define POS_OFF    (OROW_OFF + OROW_BYTES)
#define SMEM_BYTES (POS_OFF + 512*2)   // + pos_tab = 89088

typedef __attribute__((ext_vector_type(8))) short bf16x8;  // 8 bf16 (4 VGPRs)
typedef __attribute__((ext_vector_type(4))) float f32x4;

__device__ __forceinline__ short f2bf(float f) {
  union { float f; unsigned u; } v; v.f = f;
  unsigned r = v.u + 0x7FFFu + ((v.u >> 16) & 1u);   // RNE
  return (short)(r >> 16);
}

__global__ __launch_bounds__(1024, 4) void bconv_kernel(
    const float* __restrict__ x, const float* __restrict__ wts,
    const float* __restrict__ bias, const int* __restrict__ bin,
    const int* __restrict__ bout, float* __restrict__ out)
{
  extern __shared__ char smem[];
  unsigned short* pos_tab = (unsigned short*)(smem + POS_OFF);
  float* orow = (float*)(smem + OROW_OFF);

  const int t    = threadIdx.x;
  const int lane = t & 63;
  const int g    = t >> 6;      // wave id == channel-block id (16 waves)
  const int g4   = lane >> 4;
  const int n16  = lane & 15;

  const int bid   = blockIdx.x;          // 256 = 16 b * 4 strips * 4 segs
  const int b     = bid >> 4;
  const int strip = (bid >> 2) & 3;
  const int seg   = bid & 3;
  const int hs = seg * SEG;
  const int w0 = strip * WT;

  // inverse of blocks_in: channel c -> grouped position g*32+ci
  if (t < 512) pos_tab[bin[t]] = (unsigned short)t;

  // ---- weight fragments: wf[tap][nt], B-frag elem j <-> ci = g4*8+j (same kappa as A) ----
  bf16x8 wf[9][2];
  {
    const float* Wg = wts + g * (9*32*32);
#pragma unroll
    for (int tap = 0; tap < 9; ++tap) {
#pragma unroll
      for (int nt = 0; nt < 2; ++nt) {
        bf16x8 f;
#pragma unroll
        for (int j = 0; j < 8; ++j)
          f[j] = f2bf(Wg[(tap*32 + g4*8 + j)*32 + nt*16 + n16]);
        wf[tap][nt] = f;
      }
    }
  }

  const int opos0 = bout[g*32 + n16];        // scatter targets for this wave's couts
  const int opos1 = bout[g*32 + 16 + n16];

  const int c4   = (t & 127) << 2;           // flush: channel quad
  const int pixq = t >> 7;                   // flush: pixel 0..7 (+8 for 2nd slot)
  const f32x4 bias4 = *(const f32x4*)(bias + c4);

  __syncthreads();                           // pos_tab ready

  // ---- staging precompute: v = t + s*1024 over 18 cols * 128 float4 = 2304 ----
  unsigned pk[3][2];
  int go[3];
#pragma unroll
  for (int s = 0; s < 3; ++s) {
    int v = t + s*1024;
    if (v < 2304) {
      int col = v >> 7;
      int cc4 = (v & 127) << 2;
      unsigned sw = (unsigned)((col & 7) << 4);          // XOR swizzle (G4)
      unsigned o0 = ((unsigned)((col*512 + pos_tab[cc4+0])*2)) ^ sw;
      unsigned o1 = ((unsigned)((col*512 + pos_tab[cc4+1])*2)) ^ sw;
      unsigned o2 = ((unsigned)((col*512 + pos_tab[cc4+2])*2)) ^ sw;
      unsigned o3 = ((unsigned)((col*512 + pos_tab[cc4+3])*2)) ^ sw;
      pk[s][0] = o0 | (o1 << 16);
      pk[s][1] = o2 | (o3 << 16);
      int gcol = w0 - 1 + col;                            // w halo
      go[s] = (gcol >= 0 && gcol < W_) ? ((gcol*512 + cc4) * 4) : -1;
    } else {
      go[s] = -2;   // no slot-2 work for t>=256
    }
  }

  // ---- prologue: stage rows hs-1, hs, hs+1 ----
  for (int pr = 0; pr < 3; ++pr) {
    int grow = hs - 1 + pr;
    char* sb = smem + ((grow + 3) % 3) * SLOT_BYTES;
    const char* xrow = (const char*)(x + (size_t)(b*H_ + (grow < 0 ? 0 : grow)) * W_ * C_);
    bool rv = (grow >= 0) && (grow < H_);
#pragma unroll
    for (int s = 0; s < 3; ++s) {
      if (go[s] == -2) continue;
      f32x4 r = {0.f,0.f,0.f,0.f};
      if (rv && go[s] >= 0) r = *(const f32x4*)(xrow + go[s]);
      unsigned p0 = pk[s][0], p1 = pk[s][1];
      *(short*)(sb + (p0 & 0xFFFFu)) = f2bf(r[0]);
      *(short*)(sb + (p0 >> 16))     = f2bf(r[1]);
      *(short*)(sb + (p1 & 0xFFFFu)) = f2bf(r[2]);
      *(short*)(sb + (p1 >> 16))     = f2bf(r[3]);
    }
  }
  __syncthreads();

  const int gbase = g*64 + g4*16;            // byte offset of this wave's 8-ch group in a col
  const size_t outb_base = (size_t)b * H_ * W_ * C_;

  for (int h = hs; h < hs + SEG; ++h) {
    // S1: issue prefetch of row h+2 into registers (hides under MFMA phase)
    const int grow = h + 2;
    const bool want = (h <= hs + SEG - 2);
    f32x4 r0 = {0.f,0.f,0.f,0.f}, r1 = {0.f,0.f,0.f,0.f}, r2 = {0.f,0.f,0.f,0.f};
    {
      const char* xrow = (const char*)(x + (size_t)(b*H_ + (grow < H_ ? grow : 0)) * W_ * C_);
      bool rv = want && (grow < H_);
      if (rv && go[0] >= 0) r0 = *(const f32x4*)(xrow + go[0]);
      if (rv && go[1] >= 0) r1 = *(const f32x4*)(xrow + go[1]);
      if (go[2] != -2 && rv && go[2] >= 0) r2 = *(const f32x4*)(xrow + go[2]);
    }

    // S2: MFMA phase — 9 taps, A-frag = 1 ds_read_b128, 2 MFMA per tap
    f32x4 a0 = {0.f,0.f,0.f,0.f}, a1 = {0.f,0.f,0.f,0.f};
#pragma unroll
    for (int dh = 0; dh < 3; ++dh) {
      const char* sb = smem + ((h - 1 + dh + 3) % 3) * SLOT_BYTES;
#pragma unroll
      for (int dw = 0; dw < 3; ++dw) {
        int col = n16 + dw;                      // pixel m = n16, LDS col = m+dw
        int addr = (col*1024 + gbase) ^ ((col & 7) << 4);
        bf16x8 a = *(const bf16x8*)(sb + addr);
        a0 = __builtin_amdgcn_mfma_f32_16x16x32_bf16(a, wf[dh*3+dw][0], a0, 0, 0, 0);
        a1 = __builtin_amdgcn_mfma_f32_16x16x32_bf16(a, wf[dh*3+dw][1], a1, 0, 0, 0);
      }
    }
    __syncthreads();   // S3: done reading slot(h-1) & orow drained

    // S4a: scatter accumulators into orow (D layout: n=lane&15, m=(lane>>4)*4+r)
#pragma unroll
    for (int rr = 0; rr < 4; ++rr) {
      int m = (g4*4 + rr) * 512;
      orow[m + opos0] = a0[rr];
      orow[m + opos1] = a1[rr];
    }
    // S4b: write staged row h+2 into slot (overwrites row h-1)
    if (want) {
      char* sb = smem + (grow % 3) * SLOT_BYTES;
      if (go[0] != -2) {
        unsigned p0 = pk[0][0], p1 = pk[0][1];
        *(short*)(sb + (p0 & 0xFFFFu)) = f2bf(r0[0]);
        *(short*)(sb + (p0 >> 16))     = f2bf(r0[1]);
        *(short*)(sb + (p1 & 0xFFFFu)) = f2bf(r0[2]);
        *(short*)(sb + (p1 >> 16))     = f2bf(r0[3]);
      }
      if (go[1] != -2) {
        unsigned p0 = pk[1][0], p1 = pk[1][1];
        *(short*)(sb + (p0 & 0xFFFFu)) = f2bf(r1[0]);
        *(short*)(sb + (p0 >> 16))     = f2bf(r1[1]);
        *(short*)(sb + (p1 & 0xFFFFu)) = f2bf(r1[2]);
        *(short*)(sb + (p1 >> 16))     = f2bf(r1[3]);
      }
      if (go[2] != -2) {
        unsigned p0 = pk[2][0], p1 = pk[2][1];
        *(short*)(sb + (p0 & 0xFFFFu)) = f2bf(r2[0]);
        *(short*)(sb + (p0 >> 16))     = f2bf(r2[1]);
        *(short*)(sb + (p1 & 0xFFFFu)) = f2bf(r2[2]);
        *(short*)(sb + (p1 >> 16))     = f2bf(r2[3]);
      }
    }
    __syncthreads();   // S5: orow complete, slot staged

    // S6: fused bias+ReLU, fully coalesced row write
#pragma unroll
    for (int s = 0; s < 2; ++s) {
      int pix = pixq + s*8;
      f32x4 y = *(const f32x4*)(orow + pix*512 + c4);
      f32x4 o;
      o[0] = fmaxf(y[0] + bias4[0], 0.f);
      o[1] = fmaxf(y[1] + bias4[1], 0.f);
      o[2] = fmaxf(y[2] + bias4[2], 0.f);
      o[3] = fmaxf(y[3] + bias4[3], 0.f);
      *(f32x4*)(out + outb_base + (size_t)(h*W_ + w0 + pix) * C_ + c4) = o;
    }
  }
}

extern "C" void kernel_launch(void* const* d_in, const int* in_sizes, int n_in,
                              void* d_out, int out_size, void* d_ws, size_t ws_size,
                              hipStream_t stream) {
  const float* x    = (const float*)d_in[0];
  const float* wts  = (const float*)d_in[1];
  const float* bias = (const float*)d_in[2];
  const int*   bin  = (const int*)d_in[3];
  const int*   bout = (const int*)d_in[4];
  float* out = (float*)d_out;
  (void)in_sizes; (void)n_in; (void)out_size; (void)d_ws; (void)ws_size;

  bconv_kernel<<<dim3(256), dim3(1024), SMEM_BYTES, stream>>>(x, wts, bias, bin, bout, out);
}